// Round 1
// baseline (512.140 us; speedup 1.0000x reference)
//
#include <hip/hip_runtime.h>
#include <stdint.h>

#define N_TOK    16384
#define E_DIM    256
#define N_CODE   5120
#define N_SHARED 2048
#define BIGF     1e7f

#define BM  128
#define BN  128
#define BK  32
#define LDK 40                      // padded LDS row stride in bf16 elems (BK + 8)
#define NCB (N_CODE / BN)           // 40 column blocks

#define IDX_OFF ((size_t)N_TOK * E_DIM)                    // 4194304
#define D_OFF   (IDX_OFF + N_TOK)                          // 4210688
#define QL_OFF  (D_OFF + (size_t)N_TOK * N_CODE)           // 88096768

typedef float f32x4 __attribute__((ext_vector_type(4)));
typedef short bf16x8 __attribute__((ext_vector_type(8)));

__device__ __forceinline__ unsigned short bf16_rn(float f) {
    unsigned u = __float_as_uint(f);
    u += 0x7FFF + ((u >> 16) & 1);          // round-to-nearest-even
    return (unsigned short)(u >> 16);
}
__device__ __forceinline__ float bf16_to_f(unsigned short h) {
    return __uint_as_float(((unsigned)h) << 16);
}

// pack two f32x4 into hi/lo bf16x8 fragments
__device__ __forceinline__ void cvt8(f32x4 a, f32x4 b, bf16x8& hi, bf16x8& lo) {
#pragma unroll
    for (int i = 0; i < 4; ++i) {
        unsigned short h = bf16_rn(a[i]);
        hi[i] = (short)h;
        lo[i] = (short)bf16_rn(a[i] - bf16_to_f(h));
    }
#pragma unroll
    for (int i = 0; i < 4; ++i) {
        unsigned short h = bf16_rn(b[i]);
        hi[4 + i] = (short)h;
        lo[4 + i] = (short)bf16_rn(b[i] - bf16_to_f(h));
    }
}

// ---------------- K0: row norms ||x_n||^2, ||e_c||^2 ----------------
__global__ __launch_bounds__(256) void norms_kernel(const float* __restrict__ x,
                                                    const float* __restrict__ emb,
                                                    float* __restrict__ xx,
                                                    float* __restrict__ ee) {
    int wid = threadIdx.x >> 6, ln = threadIdx.x & 63;
    int row = blockIdx.x * 4 + wid;             // 0 .. 21503
    const float* src;
    float* dst;
    if (row < N_TOK) { src = x + (size_t)row * E_DIM; dst = xx + row; }
    else             { int r = row - N_TOK; src = emb + (size_t)r * E_DIM; dst = ee + r; }
    f32x4 v = ((const f32x4*)src)[ln];
    float s = v[0] * v[0] + v[1] * v[1] + v[2] * v[2] + v[3] * v[3];
#pragma unroll
    for (int sh = 32; sh; sh >>= 1) s += __shfl_xor(s, sh, 64);
    if (ln == 0) *dst = s;
}

// ---------------- K1: distance GEMM + mask + per-block argmin ----------------
__global__ __launch_bounds__(256, 2) void gemm_kernel(const float* __restrict__ x,
                                                      const float* __restrict__ emb,
                                                      const int* __restrict__ split,
                                                      const float* __restrict__ xx,
                                                      const float* __restrict__ ee,
                                                      float* __restrict__ out) {
    __shared__ short Ahi[BM * LDK], Alo[BM * LDK], Bhi[BN * LDK], Blo[BN * LDK];
    __shared__ float xxs[BM];
    __shared__ float ees[BN];
    __shared__ float redv[2][BM];
    __shared__ int   redi[2][BM];

    const int bx = blockIdx.x;      // code block 0..39
    const int by = blockIdx.y;      // token block 0..127
    const int m0 = by * BM, n0 = bx * BN;
    const int t = threadIdx.x;

    const int s1 = split[1], s2v = split[2];
    const int tmFirst = (m0 >= s1) + (m0 >= s2v);
    const int tmLast  = ((m0 + BM - 1) >= s1) + ((m0 + BM - 1) >= s2v);
    const bool rowUni = (tmFirst == tmLast);
    const int cmod = (n0 < N_SHARED) ? -1 : ((n0 - N_SHARED) >> 10);

    float* dOut = out + D_OFF;
    float* pmin = out;                               // scratch inside x_q region
    int*   pidx = (int*)(out + (size_t)N_TOK * NCB); // 16384*40 floats further in

    // fully-masked block: pure BIG fill, no GEMM
    if (cmod >= 0 && rowUni && cmod != tmFirst) {
        int row = t >> 1, ch = t & 1;
        f32x4* p = (f32x4*)(dOut + (size_t)(m0 + row) * N_CODE + n0 + ch * 64);
        f32x4 big = {BIGF, BIGF, BIGF, BIGF};
#pragma unroll
        for (int u = 0; u < 16; ++u) p[u] = big;
        if (t < BM) {
            pmin[(size_t)(m0 + t) * NCB + bx] = BIGF;
            pidx[(size_t)(m0 + t) * NCB + bx] = n0;
        }
        return;
    }

    const bool allAllowed = (cmod < 0) || (rowUni && cmod == tmFirst);

    if (t < BM) xxs[t] = xx[m0 + t];
    else        ees[t - BM] = ee[n0 + (t - BM)];

    f32x4 acc[4][4] = {};

    const int wid = t >> 6, lane = t & 63;
    const int quad = lane >> 4, ln16 = lane & 15;
    const int wr = (wid >> 1) * 64, wc = (wid & 1) * 64;

    const int srow = t >> 1, sch = (t & 1) * 16;
    const float* xg = x + (size_t)(m0 + srow) * E_DIM + sch;
    const float* eg = emb + (size_t)(n0 + srow) * E_DIM + sch;
    short* aHi = &Ahi[srow * LDK + sch];
    short* aLo = &Alo[srow * LDK + sch];
    short* bHi = &Bhi[srow * LDK + sch];
    short* bLo = &Blo[srow * LDK + sch];

    for (int kc = 0; kc < E_DIM / BK; ++kc) {
        __syncthreads();
        // stage A (tokens) hi/lo
        {
            const f32x4* xs = (const f32x4*)(xg + kc * BK);
            f32x4 f0 = xs[0], f1 = xs[1], f2 = xs[2], f3 = xs[3];
            bf16x8 h, l;
            cvt8(f0, f1, h, l);
            *(bf16x8*)aHi = h; *(bf16x8*)aLo = l;
            cvt8(f2, f3, h, l);
            *(bf16x8*)(aHi + 8) = h; *(bf16x8*)(aLo + 8) = l;
        }
        // stage B (codes) hi/lo
        {
            const f32x4* es = (const f32x4*)(eg + kc * BK);
            f32x4 f0 = es[0], f1 = es[1], f2 = es[2], f3 = es[3];
            bf16x8 h, l;
            cvt8(f0, f1, h, l);
            *(bf16x8*)bHi = h; *(bf16x8*)bLo = l;
            cvt8(f2, f3, h, l);
            *(bf16x8*)(bHi + 8) = h; *(bf16x8*)(bLo + 8) = l;
        }
        __syncthreads();

        bf16x8 ah[4], al[4], bh[4], bl[4];
#pragma unroll
        for (int i = 0; i < 4; ++i) {
            ah[i] = *(const bf16x8*)&Ahi[(wr + i * 16 + ln16) * LDK + quad * 8];
            al[i] = *(const bf16x8*)&Alo[(wr + i * 16 + ln16) * LDK + quad * 8];
        }
#pragma unroll
        for (int j = 0; j < 4; ++j) {
            bh[j] = *(const bf16x8*)&Bhi[(wc + j * 16 + ln16) * LDK + quad * 8];
            bl[j] = *(const bf16x8*)&Blo[(wc + j * 16 + ln16) * LDK + quad * 8];
        }
#pragma unroll
        for (int i = 0; i < 4; ++i)
#pragma unroll
            for (int j = 0; j < 4; ++j) {
                acc[i][j] = __builtin_amdgcn_mfma_f32_16x16x32_bf16(ah[i], bh[j], acc[i][j], 0, 0, 0);
                acc[i][j] = __builtin_amdgcn_mfma_f32_16x16x32_bf16(ah[i], bl[j], acc[i][j], 0, 0, 0);
                acc[i][j] = __builtin_amdgcn_mfma_f32_16x16x32_bf16(al[i], bh[j], acc[i][j], 0, 0, 0);
                acc[i][j] = __builtin_amdgcn_mfma_f32_16x16x32_bf16(al[i], bl[j], acc[i][j], 0, 0, 0);
            }
    }

    // epilogue: d = xx + ee - 2*dot, mask, store, row-argmin over this block
#pragma unroll
    for (int i = 0; i < 4; ++i) {
#pragma unroll
        for (int r = 0; r < 4; ++r) {
            int lm = wr + i * 16 + quad * 4 + r;     // local row (C/D: row = quad*4+reg)
            int gm = m0 + lm;
            float xv = xxs[lm];
            int tmod = (gm >= s1) + (gm >= s2v);
            float best = 3.4e38f;
            int bidx = n0;
#pragma unroll
            for (int j = 0; j < 4; ++j) {
                int lnn = wc + j * 16 + ln16;        // local col (C/D: col = lane&15)
                int gn = n0 + lnn;
                float dv = fmaf(-2.f, acc[i][j][r], xv + ees[lnn]);
                if (!allAllowed) {
                    bool ok = (gn < N_SHARED) || (((gn - N_SHARED) >> 10) == tmod);
                    if (!ok) dv = BIGF;
                }
                dOut[(size_t)gm * N_CODE + gn] = dv;
                if (dv < best) { best = dv; bidx = gn; }   // j ascending: ties keep lowest gn
            }
            // reduce across the 16 lanes of the quad (same row, different cols)
#pragma unroll
            for (int s = 1; s < 16; s <<= 1) {
                float ov = __shfl_xor(best, s, 64);
                int   oi = __shfl_xor(bidx, s, 64);
                if (ov < best || (ov == best && oi < bidx)) { best = ov; bidx = oi; }
            }
            if (ln16 == 0) { redv[wid & 1][lm] = best; redi[wid & 1][lm] = bidx; }
        }
    }
    __syncthreads();
    if (t < BM) {
        float v0 = redv[0][t]; int i0 = redi[0][t];
        float v1 = redv[1][t]; int i1 = redi[1][t];
        if (v1 < v0 || (v1 == v0 && i1 < i0)) { v0 = v1; i0 = i1; }
        pmin[(size_t)(m0 + t) * NCB + bx] = v0;
        pidx[(size_t)(m0 + t) * NCB + bx] = i0;
    }
}

// ---------------- K2: reduce 40 partials per token -> indices ----------------
__global__ __launch_bounds__(256) void reduce_kernel(float* __restrict__ out) {
    int tk = blockIdx.x * 256 + threadIdx.x;
    const float* pmin = out;
    const int* pidx = (const int*)(out + (size_t)N_TOK * NCB);
    float best = pmin[(size_t)tk * NCB];
    int bi = pidx[(size_t)tk * NCB];
    for (int j = 1; j < NCB; ++j) {
        float v = pmin[(size_t)tk * NCB + j];
        int ii = pidx[(size_t)tk * NCB + j];
        if (v < best || (v == best && ii < bi)) { best = v; bi = ii; }
    }
    out[IDX_OFF + tk] = (float)bi;
}

// ---------------- K3: gather x_q, STE output, per-block loss partials ----------------
__global__ __launch_bounds__(256) void gather_kernel(const float* __restrict__ x,
                                                     const float* __restrict__ emb,
                                                     const int* __restrict__ split,
                                                     float* __restrict__ out,
                                                     float* __restrict__ wsLoss) {
    __shared__ float ls[3];
    int t = threadIdx.x, wid = t >> 6, ln = t & 63;
    if (t < 3) ls[t] = 0.f;
    __syncthreads();
    int tok = blockIdx.x * 4 + wid;
    int idx = (int)out[IDX_OFF + tok];
    f32x4 e  = ((const f32x4*)(emb + (size_t)idx * E_DIM))[ln];
    f32x4 xv = ((const f32x4*)(x + (size_t)tok * E_DIM))[ln];
    f32x4 q;
    float s = 0.f;
#pragma unroll
    for (int c = 0; c < 4; ++c) {
        float d = e[c] - xv[c];
        q[c] = xv[c] + d;               // straight-through: x + (x_q - x)
        s = fmaf(d, d, s);
    }
    ((f32x4*)(out + (size_t)tok * E_DIM))[ln] = q;
#pragma unroll
    for (int sh = 32; sh; sh >>= 1) s += __shfl_xor(s, sh, 64);
    if (ln == 0) {
        int mod = (tok >= split[1]) + (tok >= split[2]);
        atomicAdd(&ls[mod], s);
    }
    __syncthreads();
    if (t < 3) wsLoss[blockIdx.x * 3 + t] = ls[t];
}

// ---------------- K4: final loss reduction ----------------
__global__ __launch_bounds__(256) void loss_kernel(const float* __restrict__ wsLoss,
                                                   const int* __restrict__ split,
                                                   float* __restrict__ out, int nblk) {
    __shared__ float red[256];
    float s[3] = {0.f, 0.f, 0.f};
    for (int b = threadIdx.x; b < nblk; b += 256) {
        s[0] += wsLoss[b * 3 + 0];
        s[1] += wsLoss[b * 3 + 1];
        s[2] += wsLoss[b * 3 + 2];
    }
    for (int m = 0; m < 3; ++m) {
        red[threadIdx.x] = s[m];
        __syncthreads();
        for (int st = 128; st; st >>= 1) {
            if (threadIdx.x < st) red[threadIdx.x] += red[threadIdx.x + st];
            __syncthreads();
        }
        if (threadIdx.x == 0) {
            float cnt = (float)(split[m + 1] - split[m]) * (float)E_DIM;
            float a = red[0] / cnt;
            out[QL_OFF + m] = a + 0.25f * a;   // code + beta*commit (numerically equal)
        }
        __syncthreads();
    }
}

extern "C" void kernel_launch(void* const* d_in, const int* in_sizes, int n_in,
                              void* d_out, int out_size, void* d_ws, size_t ws_size,
                              hipStream_t stream) {
    const float* x   = (const float*)d_in[0];
    const float* emb = (const float*)d_in[1];
    const int* split = (const int*)d_in[2];
    float* out = (float*)d_out;

    float* xx     = (float*)d_ws;        // 16384 floats
    float* ee     = xx + N_TOK;          // 5120 floats
    float* wsLoss = ee + N_CODE;         // 4096*3 floats
    int nblkGather = N_TOK / 4;          // 4096

    norms_kernel<<<dim3((N_TOK + N_CODE) / 4), dim3(256), 0, stream>>>(x, emb, xx, ee);
    gemm_kernel<<<dim3(NCB, N_TOK / BM), dim3(256), 0, stream>>>(x, emb, split, xx, ee, out);
    reduce_kernel<<<dim3(N_TOK / 256), dim3(256), 0, stream>>>(out);
    gather_kernel<<<dim3(nblkGather), dim3(256), 0, stream>>>(x, emb, split, out, wsLoss);
    loss_kernel<<<dim3(1), dim3(256), 0, stream>>>(wsLoss, split, out, nblkGather);
}

// Round 2
// 488.158 us; speedup vs baseline: 1.0491x; 1.0491x over previous
//
#include <hip/hip_runtime.h>
#include <stdint.h>

#define N_TOK    16384
#define E_DIM    256
#define N_CODE   5120
#define N_SHARED 2048
#define BIGF     1e7f

#define BM  128
#define BN  128
#define BK  32
#define NCB (N_CODE / BN)           // 40 column blocks
#define NKC (E_DIM / BK)            // 8 K-chunks
#define CHUNK (BM * BK)             // 4096 shorts = 8 KB per tile-chunk

#define IDX_OFF ((size_t)N_TOK * E_DIM)                    // 4194304
#define D_OFF   (IDX_OFF + N_TOK)                          // 4210688
#define QL_OFF  (D_OFF + (size_t)N_TOK * N_CODE)           // 88096768

typedef float f32x4 __attribute__((ext_vector_type(4)));
typedef short bf16x8 __attribute__((ext_vector_type(8)));
typedef short s16x4 __attribute__((ext_vector_type(4)));

typedef __attribute__((address_space(1))) const unsigned int g_u32;
typedef __attribute__((address_space(3))) unsigned int lds_u32;

__device__ __forceinline__ unsigned short bf16_rn(float f) {
    unsigned u = __float_as_uint(f);
    u += 0x7FFF + ((u >> 16) & 1);          // round-to-nearest-even
    return (unsigned short)(u >> 16);
}
__device__ __forceinline__ float bf16_to_f(unsigned short h) {
    return __uint_as_float(((unsigned)h) << 16);
}

// ---------------- K0: convert to hi/lo bf16 (fragment-swizzled) + row norms ----------------
// layout: [tile(128rows)][kc(8)][quad(4)][row(128)][8]  -> linear global_load_lds staging
__global__ __launch_bounds__(256) void convert_kernel(const float* __restrict__ x,
                                                      const float* __restrict__ emb,
                                                      float* __restrict__ xx,
                                                      float* __restrict__ ee,
                                                      short* __restrict__ xhi, short* __restrict__ xlo,
                                                      short* __restrict__ ehi, short* __restrict__ elo) {
    int wid = threadIdx.x >> 6, ln = threadIdx.x & 63;
    int row = blockIdx.x * 4 + wid;             // 0 .. 21503
    const float* src; float* nrm; short *hiA, *loA; int rl, tb;
    if (row < N_TOK) {
        src = x + (size_t)row * E_DIM; nrm = xx + row;
        tb = row >> 7; rl = row & 127; hiA = xhi; loA = xlo;
    } else {
        int r = row - N_TOK;
        src = emb + (size_t)r * E_DIM; nrm = ee + r;
        tb = r >> 7; rl = r & 127; hiA = ehi; loA = elo;
    }
    f32x4 v = ((const f32x4*)src)[ln];          // k = ln*4 .. ln*4+3
    float s = v[0]*v[0] + v[1]*v[1] + v[2]*v[2] + v[3]*v[3];
    s16x4 h, l;
#pragma unroll
    for (int c = 0; c < 4; ++c) {
        unsigned short hh = bf16_rn(v[c]);
        h[c] = (short)hh;
        l[c] = (short)bf16_rn(v[c] - bf16_to_f(hh));
    }
    int kc = ln >> 3, q = (ln >> 1) & 3, kl4 = (ln & 1) * 4;
    size_t di = ((((size_t)tb * NKC + kc) * 4 + q) * BM + rl) * 8 + kl4;
    *(s16x4*)&hiA[di] = h;
    *(s16x4*)&loA[di] = l;
#pragma unroll
    for (int sh = 32; sh; sh >>= 1) s += __shfl_xor(s, sh, 64);
    if (ln == 0) *nrm = s;
}

// ---------------- K1: distance GEMM + mask + per-block argmin ----------------
__global__ __launch_bounds__(256, 2) void gemm_kernel(const short* __restrict__ xhi,
                                                      const short* __restrict__ xlo,
                                                      const short* __restrict__ ehi,
                                                      const short* __restrict__ elo,
                                                      const int* __restrict__ split,
                                                      const float* __restrict__ xx,
                                                      const float* __restrict__ ee,
                                                      float* __restrict__ out) {
    __shared__ short Ah[CHUNK], Al[CHUNK], Bh[CHUNK], Bl[CHUNK];
    __shared__ float xxs[BM];
    __shared__ float ees[BN];
    __shared__ float redv[2][BM];
    __shared__ int   redi[2][BM];

    const int bx = blockIdx.x;      // code block 0..39
    const int by = blockIdx.y;      // token block 0..127
    const int m0 = by * BM, n0 = bx * BN;
    const int t = threadIdx.x;

    const int s1 = split[1], s2v = split[2];
    const int tmFirst = (m0 >= s1) + (m0 >= s2v);
    const int tmLast  = ((m0 + BM - 1) >= s1) + ((m0 + BM - 1) >= s2v);
    const bool rowUni = (tmFirst == tmLast);
    const int cmod = (n0 < N_SHARED) ? -1 : ((n0 - N_SHARED) >> 10);

    float* dOut = out + D_OFF;
    float* pmin = out;                               // scratch inside x_q region
    int*   pidx = (int*)(out + (size_t)N_TOK * NCB); // 16384*40 floats further in

    // fully-masked block: pure BIG fill, no GEMM
    if (cmod >= 0 && rowUni && cmod != tmFirst) {
        int row = t >> 1, ch = t & 1;
        f32x4* p = (f32x4*)(dOut + (size_t)(m0 + row) * N_CODE + n0 + ch * 64);
        f32x4 big = {BIGF, BIGF, BIGF, BIGF};
#pragma unroll
        for (int u = 0; u < 16; ++u) p[u] = big;
        if (t < BM) {
            pmin[(size_t)(m0 + t) * NCB + bx] = BIGF;
            pidx[(size_t)(m0 + t) * NCB + bx] = n0;
        }
        return;
    }

    const bool allAllowed = (cmod < 0) || (rowUni && cmod == tmFirst);

    if (t < BM) xxs[t] = xx[m0 + t];
    else        ees[t - BM] = ee[n0 + (t - BM)];

    f32x4 acc[4][4] = {};

    const int wid = t >> 6, lane = t & 63;
    const int quad = lane >> 4, ln16 = lane & 15;
    const int wr = (wid >> 1) * 64, wc = (wid & 1) * 64;

    const short* aHiG = xhi + (size_t)by * NKC * CHUNK;
    const short* aLoG = xlo + (size_t)by * NKC * CHUNK;
    const short* bHiG = ehi + (size_t)bx * NKC * CHUNK;
    const short* bLoG = elo + (size_t)bx * NKC * CHUNK;
    const int tOff = t * 8;                     // shorts (16 B per thread per pass)

    for (int kc = 0; kc < NKC; ++kc) {
        __syncthreads();                        // LDS reuse from previous iter
        const int co = kc * CHUNK;
#pragma unroll
        for (int p = 0; p < 2; ++p) {
            int o = p * 2048 + tOff;            // shorts
            __builtin_amdgcn_global_load_lds((g_u32*)(aHiG + co + o), (lds_u32*)&Ah[o], 16, 0, 0);
            __builtin_amdgcn_global_load_lds((g_u32*)(aLoG + co + o), (lds_u32*)&Al[o], 16, 0, 0);
            __builtin_amdgcn_global_load_lds((g_u32*)(bHiG + co + o), (lds_u32*)&Bh[o], 16, 0, 0);
            __builtin_amdgcn_global_load_lds((g_u32*)(bLoG + co + o), (lds_u32*)&Bl[o], 16, 0, 0);
        }
        __syncthreads();

        bf16x8 ah[4], al[4], bh[4], bl[4];
#pragma unroll
        for (int i = 0; i < 4; ++i) {
            int a = (quad * BM + wr + i * 16 + ln16) * 8;
            ah[i] = *(const bf16x8*)&Ah[a];
            al[i] = *(const bf16x8*)&Al[a];
        }
#pragma unroll
        for (int j = 0; j < 4; ++j) {
            int b = (quad * BM + wc + j * 16 + ln16) * 8;
            bh[j] = *(const bf16x8*)&Bh[b];
            bl[j] = *(const bf16x8*)&Bl[b];
        }
#pragma unroll
        for (int i = 0; i < 4; ++i)
#pragma unroll
            for (int j = 0; j < 4; ++j) {
                acc[i][j] = __builtin_amdgcn_mfma_f32_16x16x32_bf16(ah[i], bh[j], acc[i][j], 0, 0, 0);
                acc[i][j] = __builtin_amdgcn_mfma_f32_16x16x32_bf16(ah[i], bl[j], acc[i][j], 0, 0, 0);
                acc[i][j] = __builtin_amdgcn_mfma_f32_16x16x32_bf16(al[i], bh[j], acc[i][j], 0, 0, 0);
            }
    }

    // epilogue: d = xx + ee - 2*dot, mask, store, row-argmin over this block
#pragma unroll
    for (int i = 0; i < 4; ++i) {
#pragma unroll
        for (int r = 0; r < 4; ++r) {
            int lm = wr + i * 16 + quad * 4 + r;     // local row (C/D: row = quad*4+reg)
            int gm = m0 + lm;
            float xv = xxs[lm];
            int tmod = (gm >= s1) + (gm >= s2v);
            float best = 3.4e38f;
            int bidx = n0;
#pragma unroll
            for (int j = 0; j < 4; ++j) {
                int lnn = wc + j * 16 + ln16;        // local col (C/D: col = lane&15)
                int gn = n0 + lnn;
                float dv = fmaf(-2.f, acc[i][j][r], xv + ees[lnn]);
                if (!allAllowed) {
                    bool ok = (gn < N_SHARED) || (((gn - N_SHARED) >> 10) == tmod);
                    if (!ok) dv = BIGF;
                }
                dOut[(size_t)gm * N_CODE + gn] = dv;
                if (dv < best) { best = dv; bidx = gn; }   // j ascending: ties keep lowest gn
            }
#pragma unroll
            for (int s = 1; s < 16; s <<= 1) {
                float ov = __shfl_xor(best, s, 64);
                int   oi = __shfl_xor(bidx, s, 64);
                if (ov < best || (ov == best && oi < bidx)) { best = ov; bidx = oi; }
            }
            if (ln16 == 0) { redv[wid & 1][lm] = best; redi[wid & 1][lm] = bidx; }
        }
    }
    __syncthreads();
    if (t < BM) {
        float v0 = redv[0][t]; int i0 = redi[0][t];
        float v1 = redv[1][t]; int i1 = redi[1][t];
        if (v1 < v0 || (v1 == v0 && i1 < i0)) { v0 = v1; i0 = i1; }
        pmin[(size_t)(m0 + t) * NCB + bx] = v0;
        pidx[(size_t)(m0 + t) * NCB + bx] = i0;
    }
}

// ---------------- K2: reduce 40 partials per token -> indices ----------------
__global__ __launch_bounds__(256) void reduce_kernel(float* __restrict__ out) {
    int tk = blockIdx.x * 256 + threadIdx.x;
    const float* pmin = out;
    const int* pidx = (const int*)(out + (size_t)N_TOK * NCB);
    float best = pmin[(size_t)tk * NCB];
    int bi = pidx[(size_t)tk * NCB];
    for (int j = 1; j < NCB; ++j) {
        float v = pmin[(size_t)tk * NCB + j];
        int ii = pidx[(size_t)tk * NCB + j];
        if (v < best || (v == best && ii < bi)) { best = v; bi = ii; }
    }
    out[IDX_OFF + tk] = (float)bi;
}

// ---------------- K3: gather x_q, STE output, per-block loss partials ----------------
__global__ __launch_bounds__(256) void gather_kernel(const float* __restrict__ x,
                                                     const float* __restrict__ emb,
                                                     const int* __restrict__ split,
                                                     float* __restrict__ out,
                                                     float* __restrict__ wsLoss) {
    __shared__ float ls[3];
    int t = threadIdx.x, wid = t >> 6, ln = t & 63;
    if (t < 3) ls[t] = 0.f;
    __syncthreads();
    int tok = blockIdx.x * 4 + wid;
    int idx = (int)out[IDX_OFF + tok];
    f32x4 e  = ((const f32x4*)(emb + (size_t)idx * E_DIM))[ln];
    f32x4 xv = ((const f32x4*)(x + (size_t)tok * E_DIM))[ln];
    f32x4 q;
    float s = 0.f;
#pragma unroll
    for (int c = 0; c < 4; ++c) {
        float d = e[c] - xv[c];
        q[c] = xv[c] + d;               // straight-through: x + (x_q - x)
        s = fmaf(d, d, s);
    }
    ((f32x4*)(out + (size_t)tok * E_DIM))[ln] = q;
#pragma unroll
    for (int sh = 32; sh; sh >>= 1) s += __shfl_xor(s, sh, 64);
    if (ln == 0) {
        int mod = (tok >= split[1]) + (tok >= split[2]);
        atomicAdd(&ls[mod], s);
    }
    __syncthreads();
    if (t < 3) wsLoss[blockIdx.x * 3 + t] = ls[t];
}

// ---------------- K4: final loss reduction ----------------
__global__ __launch_bounds__(256) void loss_kernel(const float* __restrict__ wsLoss,
                                                   const int* __restrict__ split,
                                                   float* __restrict__ out, int nblk) {
    __shared__ float red[256];
    float s[3] = {0.f, 0.f, 0.f};
    for (int b = threadIdx.x; b < nblk; b += 256) {
        s[0] += wsLoss[b * 3 + 0];
        s[1] += wsLoss[b * 3 + 1];
        s[2] += wsLoss[b * 3 + 2];
    }
    for (int m = 0; m < 3; ++m) {
        red[threadIdx.x] = s[m];
        __syncthreads();
        for (int st = 128; st; st >>= 1) {
            if (threadIdx.x < st) red[threadIdx.x] += red[threadIdx.x + st];
            __syncthreads();
        }
        if (threadIdx.x == 0) {
            float cnt = (float)(split[m + 1] - split[m]) * (float)E_DIM;
            float a = red[0] / cnt;
            out[QL_OFF + m] = a + 0.25f * a;   // code + beta*commit (numerically equal)
        }
        __syncthreads();
    }
}

extern "C" void kernel_launch(void* const* d_in, const int* in_sizes, int n_in,
                              void* d_out, int out_size, void* d_ws, size_t ws_size,
                              hipStream_t stream) {
    const float* x   = (const float*)d_in[0];
    const float* emb = (const float*)d_in[1];
    const int* split = (const int*)d_in[2];
    float* out = (float*)d_out;

    float* xx     = (float*)d_ws;          // 16384 f32
    float* ee     = xx + N_TOK;            // 5120 f32
    float* wsLoss = ee + N_CODE;           // 4096*3 f32
    short* xhi    = (short*)(wsLoss + 4096 * 3);
    short* xlo    = xhi + (size_t)N_TOK * E_DIM;
    short* ehi    = xlo + (size_t)N_TOK * E_DIM;
    short* elo    = ehi + (size_t)N_CODE * E_DIM;
    int nblkGather = N_TOK / 4;            // 4096

    convert_kernel<<<dim3((N_TOK + N_CODE) / 4), dim3(256), 0, stream>>>(x, emb, xx, ee, xhi, xlo, ehi, elo);
    gemm_kernel<<<dim3(NCB, N_TOK / BM), dim3(256), 0, stream>>>(xhi, xlo, ehi, elo, split, xx, ee, out);
    reduce_kernel<<<dim3(N_TOK / 256), dim3(256), 0, stream>>>(out);
    gather_kernel<<<dim3(nblkGather), dim3(256), 0, stream>>>(x, emb, split, out, wsLoss);
    loss_kernel<<<dim3(1), dim3(256), 0, stream>>>(wsLoss, split, out, nblkGather);
}